// Round 1
// baseline (639.312 us; speedup 1.0000x reference)
//
#include <hip/hip_runtime.h>
#include <math.h>

#define N_NODES 10000
#define N_EDGES 160000
#define FDIM    512
#define DOUT    256

// ---------------------------------------------------------------------------
// Preprocessing: degrees, norms, destination-sorted CSR (rebuilt every call —
// no cross-call state; d_ws is poisoned before each timed launch).
// ---------------------------------------------------------------------------

__global__ void k_zero(float* deg_g, float* deg_c, int* counts, int* fill, int n) {
    int i = blockIdx.x * blockDim.x + threadIdx.x;
    if (i < n) { deg_g[i] = 0.f; deg_c[i] = 0.f; counts[i] = 0; fill[i] = 0; }
}

__global__ void k_edge_deg(const int* __restrict__ row, const int* __restrict__ col,
                           const float* __restrict__ w,
                           float* deg_g, float* deg_c, int* counts, int E) {
    int e = blockIdx.x * blockDim.x + threadIdx.x;
    if (e >= E) return;
    int r = row[e], c = col[e];
    float wv = w[e];
    atomicAdd(&deg_g[c], wv);              // GCN: segment_sum(w, col)
    if (r != c) atomicAdd(&deg_c[r], wv);  // Cheb: self-loops removed, sum by row
    atomicAdd(&counts[c], 1);              // CSR by destination (col)
}

__global__ void k_dinv(const float* __restrict__ deg_g, const float* __restrict__ deg_c,
                       float* dinv_g, float* dinv_c, int n) {
    int i = blockIdx.x * blockDim.x + threadIdx.x;
    if (i >= n) return;
    dinv_g[i] = rsqrtf(deg_g[i] + 1.0f);   // +1 = self-loop weight; always > 0
    float d = deg_c[i];
    dinv_c[i] = d > 0.f ? rsqrtf(d) : 0.f;
}

// Exclusive scan of counts -> rp[0..n], single block of 1024 threads.
__global__ __launch_bounds__(1024) void k_scan(const int* __restrict__ counts,
                                               int* __restrict__ rp, int n) {
    __shared__ int sdata[1024];
    __shared__ int s_carry;
    int tid = threadIdx.x;
    if (tid == 0) s_carry = 0;
    __syncthreads();
    for (int base = 0; base < n; base += 1024) {
        int i = base + tid;
        int v = (i < n) ? counts[i] : 0;
        sdata[tid] = v;
        __syncthreads();
        for (int offs = 1; offs < 1024; offs <<= 1) {
            int t = (tid >= offs) ? sdata[tid - offs] : 0;
            __syncthreads();
            sdata[tid] += t;
            __syncthreads();
        }
        int incl = sdata[tid];
        int carry = s_carry;
        if (i < n) rp[i] = carry + incl - v;
        __syncthreads();
        if (tid == 0) s_carry = carry + sdata[1023];
        __syncthreads();
    }
    if (tid == 0) rp[n] = s_carry;
}

__global__ void k_fill(const int* __restrict__ row, const int* __restrict__ col,
                       const float* __restrict__ w,
                       const float* __restrict__ dinv_g, const float* __restrict__ dinv_c,
                       const int* __restrict__ rp, int* __restrict__ fill,
                       int* __restrict__ srcs, float* __restrict__ n_g,
                       float* __restrict__ n_c, int E) {
    int e = blockIdx.x * blockDim.x + threadIdx.x;
    if (e >= E) return;
    int r = row[e], c = col[e];
    float wv = w[e];
    float ng = dinv_g[r] * wv * dinv_g[c];
    float w0 = (r == c) ? 0.f : wv;
    float nc = -(dinv_c[r] * w0 * dinv_c[c]);   // store NEGATED: lhat is plain FMA-sum
    int pos = rp[c] + atomicAdd(&fill[c], 1);
    srcs[pos] = r;
    n_g[pos]  = ng;
    n_c[pos]  = nc;
}

// ---------------------------------------------------------------------------
// Tiled fp32 GEMM: C[M,N] = A[M,K] @ B[K,N] (+C) (+bias) (celu)
// 64x64 tile, BK=16, 256 threads, 4x4 microtile per thread.
// ---------------------------------------------------------------------------

#define BM 64
#define BN 64
#define BK 16

__global__ __launch_bounds__(256) void k_gemm(
    const float* __restrict__ A, const float* __restrict__ B, float* __restrict__ C,
    int M, int K, int N, const float* __restrict__ bias, int accFlag, int celuFlag)
{
    __shared__ float As[BK][BM + 4];   // transposed: As[k][m]; +4 keeps 16B align, breaks bank stride
    __shared__ float Bs[BK][BN + 4];
    const int bm  = blockIdx.x * BM;
    const int bn  = blockIdx.y * BN;
    const int tid = threadIdx.x;
    const int tx  = tid & 15;
    const int ty  = tid >> 4;
    const int aRow = tid >> 2;          // 0..63
    const int aCol = (tid & 3) << 2;    // 0,4,8,12
    const int bRow = tid >> 4;          // 0..15
    const int bCol = (tid & 15) << 2;   // 0..60
    const bool aValid = (bm + aRow) < M;
    const float* Ap = A + (size_t)(bm + aRow) * K + aCol;
    const float* Bp = B + (size_t)bRow * N + bn + bCol;
    float acc[4][4] = {};

    for (int k0 = 0; k0 < K; k0 += BK) {
        float4 av = make_float4(0.f, 0.f, 0.f, 0.f);
        if (aValid) av = *(const float4*)(Ap + k0);
        float4 bv = *(const float4*)(Bp + (size_t)k0 * N);
        __syncthreads();
        As[aCol + 0][aRow] = av.x;
        As[aCol + 1][aRow] = av.y;
        As[aCol + 2][aRow] = av.z;
        As[aCol + 3][aRow] = av.w;
        *(float4*)&Bs[bRow][bCol] = bv;
        __syncthreads();
#pragma unroll
        for (int k = 0; k < BK; ++k) {
            float4 a4 = *(const float4*)&As[k][ty << 2];
            float4 b4 = *(const float4*)&Bs[k][tx << 2];
            float ar[4] = {a4.x, a4.y, a4.z, a4.w};
            float br[4] = {b4.x, b4.y, b4.z, b4.w};
#pragma unroll
            for (int i = 0; i < 4; ++i)
#pragma unroll
                for (int j = 0; j < 4; ++j)
                    acc[i][j] = fmaf(ar[i], br[j], acc[i][j]);
        }
    }
#pragma unroll
    for (int i = 0; i < 4; ++i) {
        int r = bm + (ty << 2) + i;
        if (r >= M) continue;
        float* Cp = C + (size_t)r * N + bn + (tx << 2);
#pragma unroll
        for (int j = 0; j < 4; ++j) {
            float v = acc[i][j];
            if (accFlag)  v += Cp[j];
            if (bias)     v += bias[bn + (tx << 2) + j];
            if (celuFlag) v = v > 0.f ? v : expm1f(v);
            Cp[j] = v;
        }
    }
}

// ---------------------------------------------------------------------------
// Sparse aggregation over destination-sorted CSR. One block (128 thr) per
// node; each thread owns a float4 feature slice (512 = 128*4).
// mode 0 (GCN):  out = celu( dinv[c]^2 * h[c] + sum_e n_g*h[src] + bias )
// mode 1 (Cheb): out = sA * (sum_e n_c*h[src]) + sB * other[c]   (in-place OK)
// ---------------------------------------------------------------------------

__global__ __launch_bounds__(128) void k_agg(
    const float* __restrict__ h, const int* __restrict__ srcs,
    const float* __restrict__ nrm, const int* __restrict__ rp,
    const float* __restrict__ dinv_g, const float* __restrict__ bias,
    const float* __restrict__ other, float* __restrict__ out,
    float sA, float sB, int mode)
{
    const int c = blockIdx.x;
    const int f = threadIdx.x << 2;
    float4 acc = make_float4(0.f, 0.f, 0.f, 0.f);
    if (mode == 0) {
        float dv = dinv_g[c];
        float d2 = dv * dv;
        float4 hv = *(const float4*)(h + (size_t)c * FDIM + f);
        acc.x = d2 * hv.x; acc.y = d2 * hv.y; acc.z = d2 * hv.z; acc.w = d2 * hv.w;
    }
    const int e0 = rp[c], e1 = rp[c + 1];
    for (int e = e0; e < e1; ++e) {
        int s = srcs[e];
        float nv = nrm[e];
        float4 hv = *(const float4*)(h + (size_t)s * FDIM + f);
        acc.x = fmaf(nv, hv.x, acc.x);
        acc.y = fmaf(nv, hv.y, acc.y);
        acc.z = fmaf(nv, hv.z, acc.z);
        acc.w = fmaf(nv, hv.w, acc.w);
    }
    float* op = out + (size_t)c * FDIM + f;
    if (mode == 0) {
        float4 bv = *(const float4*)(bias + f);
        float4 r;
        r.x = acc.x + bv.x; r.y = acc.y + bv.y; r.z = acc.z + bv.z; r.w = acc.w + bv.w;
        r.x = r.x > 0.f ? r.x : expm1f(r.x);
        r.y = r.y > 0.f ? r.y : expm1f(r.y);
        r.z = r.z > 0.f ? r.z : expm1f(r.z);
        r.w = r.w > 0.f ? r.w : expm1f(r.w);
        *(float4*)op = r;
    } else {
        float4 ov = make_float4(0.f, 0.f, 0.f, 0.f);
        if (other) ov = *(const float4*)(other + (size_t)c * FDIM + f);
        float4 r;
        r.x = sA * acc.x + sB * ov.x;
        r.y = sA * acc.y + sB * ov.y;
        r.z = sA * acc.z + sB * ov.z;
        r.w = sA * acc.w + sB * ov.w;
        *(float4*)op = r;
    }
}

// ---------------------------------------------------------------------------

extern "C" void kernel_launch(void* const* d_in, const int* in_sizes, int n_in,
                              void* d_out, int out_size, void* d_ws, size_t ws_size,
                              hipStream_t stream) {
    const float* x  = (const float*)d_in[0];
    const int*   ei = (const int*)d_in[1];
    const float* ew = (const float*)d_in[2];
    const float* W1 = (const float*)d_in[3];
    const float* b1 = (const float*)d_in[4];
    const float* W2 = (const float*)d_in[5];
    const float* b2 = (const float*)d_in[6];
    const float* Wc = (const float*)d_in[7];
    const float* bc = (const float*)d_in[8];
    float* out = (float*)d_out;

    const int* row = ei;
    const int* col = ei + N_EDGES;

    char* ws = (char*)d_ws;
    size_t off = 0;
    auto alloc = [&](size_t bytes) -> void* {
        void* p = ws + off;
        off += (bytes + 255) & ~(size_t)255;
        return p;
    };
    float* bufA   = (float*)alloc((size_t)N_NODES * FDIM * 4);   // h1 / h2 / T1
    float* bufB   = (float*)alloc((size_t)N_NODES * FDIM * 4);   // h1a / h2a(T0) / T2
    float* deg_g  = (float*)alloc((size_t)N_NODES * 4);
    float* deg_c  = (float*)alloc((size_t)N_NODES * 4);
    float* dinv_g = (float*)alloc((size_t)N_NODES * 4);
    float* dinv_c = (float*)alloc((size_t)N_NODES * 4);
    int*   counts = (int*)alloc((size_t)N_NODES * 4);
    int*   fill   = (int*)alloc((size_t)N_NODES * 4);
    int*   rp     = (int*)alloc((size_t)(N_NODES + 1) * 4);
    int*   srcs   = (int*)alloc((size_t)N_EDGES * 4);
    float* n_g    = (float*)alloc((size_t)N_EDGES * 4);
    float* n_c    = (float*)alloc((size_t)N_EDGES * 4);

    const int TB = 256;
    dim3 nodeGrid((N_NODES + TB - 1) / TB);
    dim3 edgeGrid((N_EDGES + TB - 1) / TB);

    // ---- preprocessing: norms + destination-sorted CSR ----
    hipLaunchKernelGGL(k_zero, nodeGrid, dim3(TB), 0, stream, deg_g, deg_c, counts, fill, N_NODES);
    hipLaunchKernelGGL(k_edge_deg, edgeGrid, dim3(TB), 0, stream, row, col, ew, deg_g, deg_c, counts, N_EDGES);
    hipLaunchKernelGGL(k_dinv, nodeGrid, dim3(TB), 0, stream, deg_g, deg_c, dinv_g, dinv_c, N_NODES);
    hipLaunchKernelGGL(k_scan, dim3(1), dim3(1024), 0, stream, counts, rp, N_NODES);
    hipLaunchKernelGGL(k_fill, edgeGrid, dim3(TB), 0, stream, row, col, ew, dinv_g, dinv_c,
                       rp, fill, srcs, n_g, n_c, N_EDGES);

    auto gemm = [&](const float* A, const float* B, float* C, int M, int K, int N,
                    const float* bias, int accFlag, int celuFlag) {
        dim3 g((M + BM - 1) / BM, N / BN);
        hipLaunchKernelGGL(k_gemm, g, dim3(256), 0, stream, A, B, C, M, K, N, bias, accFlag, celuFlag);
    };

    // ---- GCN layer 1: h1 = x@W1; h1a = celu(agg(h1) + b1) ----
    gemm(x, W1, bufA, N_NODES, FDIM, FDIM, nullptr, 0, 0);
    hipLaunchKernelGGL(k_agg, dim3(N_NODES), dim3(128), 0, stream,
                       bufA, srcs, n_g, rp, dinv_g, b1, nullptr, bufB, 1.f, 0.f, 0);

    // ---- GCN layer 2: h2 = h1a@W2; h2a = celu(agg(h2) + b2) ----
    gemm(bufB, W2, bufA, N_NODES, FDIM, FDIM, nullptr, 0, 0);
    hipLaunchKernelGGL(k_agg, dim3(N_NODES), dim3(128), 0, stream,
                       bufA, srcs, n_g, rp, dinv_g, b2, nullptr, bufB, 1.f, 0.f, 0);
    // bufB = T0 (h2a)

    // ---- Cheb layer ----
    // T1 = lhat(T0)   (n_c stored negated, so plain sum)
    hipLaunchKernelGGL(k_agg, dim3(N_NODES), dim3(128), 0, stream,
                       bufB, srcs, n_c, rp, nullptr, nullptr, nullptr, bufA, 1.f, 0.f, 1);
    // out = T0@Wc[0]
    gemm(bufB, Wc + 0 * FDIM * DOUT, out, N_NODES, FDIM, DOUT, nullptr, 0, 0);
    // out += T1@Wc[1]
    gemm(bufA, Wc + 1 * FDIM * DOUT, out, N_NODES, FDIM, DOUT, nullptr, 1, 0);
    // T2 = 2*lhat(T1) - T0   (in-place over bufB)
    hipLaunchKernelGGL(k_agg, dim3(N_NODES), dim3(128), 0, stream,
                       bufA, srcs, n_c, rp, nullptr, nullptr, bufB, bufB, 2.f, -1.f, 1);
    // out = celu(out + T2@Wc[2] + bc)
    gemm(bufB, Wc + 2 * FDIM * DOUT, out, N_NODES, FDIM, DOUT, bc, 1, 1);
}

// Round 2
// 417.564 us; speedup vs baseline: 1.5311x; 1.5311x over previous
//
#include <hip/hip_runtime.h>
#include <math.h>

#define N_NODES 10000
#define N_EDGES 160000
#define FDIM    512
#define DOUT    256

typedef unsigned short ushort_t;
typedef unsigned int   uint_t;
typedef __attribute__((ext_vector_type(8))) short bf16x8;
typedef __attribute__((ext_vector_type(4))) float f32x4;

// ---------------------------------------------------------------------------
// helpers: bf16 <-> f32
// ---------------------------------------------------------------------------
__device__ inline ushort_t f2bf(float f) {
    uint_t u = __float_as_uint(f);
    u += 0x7fffu + ((u >> 16) & 1u);        // round-to-nearest-even
    return (ushort_t)(u >> 16);
}
__device__ inline void bf2f8(uint4 u, float* v) {
    v[0] = __uint_as_float(u.x << 16); v[1] = __uint_as_float(u.x & 0xffff0000u);
    v[2] = __uint_as_float(u.y << 16); v[3] = __uint_as_float(u.y & 0xffff0000u);
    v[4] = __uint_as_float(u.z << 16); v[5] = __uint_as_float(u.z & 0xffff0000u);
    v[6] = __uint_as_float(u.w << 16); v[7] = __uint_as_float(u.w & 0xffff0000u);
}
__device__ inline uint4 f2bf8v(const float* v) {
    uint4 u;
    u.x = (uint_t)f2bf(v[0]) | ((uint_t)f2bf(v[1]) << 16);
    u.y = (uint_t)f2bf(v[2]) | ((uint_t)f2bf(v[3]) << 16);
    u.z = (uint_t)f2bf(v[4]) | ((uint_t)f2bf(v[5]) << 16);
    u.w = (uint_t)f2bf(v[6]) | ((uint_t)f2bf(v[7]) << 16);
    return u;
}

// ---------------------------------------------------------------------------
// Preprocessing (fp32): degrees, norms, destination-sorted CSR
// ---------------------------------------------------------------------------
__global__ void k_zero(float* deg_g, float* deg_c, int* counts, int* fill, int n) {
    int i = blockIdx.x * blockDim.x + threadIdx.x;
    if (i < n) { deg_g[i] = 0.f; deg_c[i] = 0.f; counts[i] = 0; fill[i] = 0; }
}

__global__ void k_edge_deg(const int* __restrict__ row, const int* __restrict__ col,
                           const float* __restrict__ w,
                           float* deg_g, float* deg_c, int* counts, int E) {
    int e = blockIdx.x * blockDim.x + threadIdx.x;
    if (e >= E) return;
    int r = row[e], c = col[e];
    float wv = w[e];
    atomicAdd(&deg_g[c], wv);
    if (r != c) atomicAdd(&deg_c[r], wv);
    atomicAdd(&counts[c], 1);
}

__global__ void k_dinv(const float* __restrict__ deg_g, const float* __restrict__ deg_c,
                       float* dinv_g, float* dinv_c, int n) {
    int i = blockIdx.x * blockDim.x + threadIdx.x;
    if (i >= n) return;
    dinv_g[i] = rsqrtf(deg_g[i] + 1.0f);
    float d = deg_c[i];
    dinv_c[i] = d > 0.f ? rsqrtf(d) : 0.f;
}

__global__ __launch_bounds__(1024) void k_scan(const int* __restrict__ counts,
                                               int* __restrict__ rp, int n) {
    __shared__ int sdata[1024];
    __shared__ int s_carry;
    int tid = threadIdx.x;
    if (tid == 0) s_carry = 0;
    __syncthreads();
    for (int base = 0; base < n; base += 1024) {
        int i = base + tid;
        int v = (i < n) ? counts[i] : 0;
        sdata[tid] = v;
        __syncthreads();
        for (int offs = 1; offs < 1024; offs <<= 1) {
            int t = (tid >= offs) ? sdata[tid - offs] : 0;
            __syncthreads();
            sdata[tid] += t;
            __syncthreads();
        }
        int incl = sdata[tid];
        int carry = s_carry;
        if (i < n) rp[i] = carry + incl - v;
        __syncthreads();
        if (tid == 0) s_carry = carry + sdata[1023];
        __syncthreads();
    }
    if (tid == 0) rp[n] = s_carry;
}

__global__ void k_fill(const int* __restrict__ row, const int* __restrict__ col,
                       const float* __restrict__ w,
                       const float* __restrict__ dinv_g, const float* __restrict__ dinv_c,
                       const int* __restrict__ rp, int* __restrict__ fill,
                       int* __restrict__ srcs, float* __restrict__ n_g,
                       float* __restrict__ n_c, int E) {
    int e = blockIdx.x * blockDim.x + threadIdx.x;
    if (e >= E) return;
    int r = row[e], c = col[e];
    float wv = w[e];
    float ng = dinv_g[r] * wv * dinv_g[c];
    float w0 = (r == c) ? 0.f : wv;
    float nc = -(dinv_c[r] * w0 * dinv_c[c]);   // negated: lhat is then a plain sum
    int pos = rp[c] + atomicAdd(&fill[c], 1);
    srcs[pos] = r;
    n_g[pos]  = ng;
    n_c[pos]  = nc;
}

// ---------------------------------------------------------------------------
// fp32 -> bf16 conversions / weight repack
// ---------------------------------------------------------------------------
__global__ void k_f2b(const float* __restrict__ src, ushort_t* __restrict__ dst, int n4) {
    int i = blockIdx.x * blockDim.x + threadIdx.x;
    if (i >= n4) return;
    float4 v = *(const float4*)(src + (size_t)i * 4);
    uint2 p;
    p.x = (uint_t)f2bf(v.x) | ((uint_t)f2bf(v.y) << 16);
    p.y = (uint_t)f2bf(v.z) | ((uint_t)f2bf(v.w) << 16);
    *(uint2*)(dst + (size_t)i * 4) = p;
}

// W[K][N] fp32 -> Wt[N][K] bf16
__global__ void k_wt(const float* __restrict__ W, ushort_t* __restrict__ Wt, int K, int N) {
    int t = blockIdx.x * blockDim.x + threadIdx.x;
    if (t >= K * N) return;
    int n = t % N, k = t / N;
    Wt[(size_t)n * K + k] = f2bf(W[(size_t)k * N + n]);
}

// Wc[3][512][256] fp32 -> Wct[256][1536] bf16 with Wct[n][kk*512+d] = Wc[kk][d][n]
__global__ void k_wc(const float* __restrict__ Wc, ushort_t* __restrict__ Wct) {
    int t = blockIdx.x * blockDim.x + threadIdx.x;
    if (t >= 3 * 512 * 256) return;
    int n = t & 255, d = (t >> 8) & 511, kk = t >> 17;
    Wct[(size_t)n * 1536 + kk * 512 + d] = f2bf(Wc[((size_t)kk * 512 + d) * 256 + n]);
}

// ---------------------------------------------------------------------------
// bf16 MFMA GEMM, LDS-free: fragments loaded directly from global (L1/L2).
// A[M][K] bf16 row-major, Bt[N][K] bf16 row-major (i.e. B transposed).
// Block 256 thr = 4 waves, 64x64 tile, each wave 32x32 = 2x2 MFMA tiles.
// XCD swizzle: block lid%8 -> XCD j; XCD j owns contiguous row-block slice,
// so its A working set (~1.3 MB for K=512) stays in its private 4 MB L2.
// Epilogue: bf16 store (outB) or fp32 bias+celu store (outF).
// ---------------------------------------------------------------------------
__global__ __launch_bounds__(256) void k_bgemm(
    const ushort_t* __restrict__ A, const ushort_t* __restrict__ Bt,
    int M, int K, int N,
    const float* __restrict__ bias,
    ushort_t* __restrict__ outB, float* __restrict__ outF)
{
    const int mb    = (M + 63) >> 6;
    const int chunk = (mb + 7) >> 3;
    const int nyb   = N >> 6;
    int lid = blockIdx.x;
    int j = lid & 7;
    int t = lid >> 3;
    int bx = j * chunk + t / nyb;
    int by = t % nyb;
    if (bx >= mb) return;

    const int tid  = threadIdx.x;
    const int w    = tid >> 6;
    const int lane = tid & 63;
    const int wm   = (w & 1) << 5;
    const int wn   = (w >> 1) << 5;
    const int l15  = lane & 15;
    const int quad = lane >> 4;
    const int bm   = bx << 6, bn = by << 6;

    int r0 = bm + wm + l15;
    int r1 = r0 + 16;
    r0 = min(r0, M - 1);
    r1 = min(r1, M - 1);
    const ushort_t* a0 = A + (size_t)r0 * K + quad * 8;
    const ushort_t* a1 = A + (size_t)r1 * K + quad * 8;
    const int c0 = bn + wn + l15;                 // N is a multiple of 64: in-bounds
    const ushort_t* b0 = Bt + (size_t)c0 * K + quad * 8;
    const ushort_t* b1 = b0 + (size_t)16 * K;

    f32x4 acc00 = {0.f, 0.f, 0.f, 0.f};
    f32x4 acc01 = {0.f, 0.f, 0.f, 0.f};
    f32x4 acc10 = {0.f, 0.f, 0.f, 0.f};
    f32x4 acc11 = {0.f, 0.f, 0.f, 0.f};

    for (int k = 0; k < K; k += 32) {
        bf16x8 af0 = *(const bf16x8*)(a0 + k);
        bf16x8 af1 = *(const bf16x8*)(a1 + k);
        bf16x8 bf0 = *(const bf16x8*)(b0 + k);
        bf16x8 bf1 = *(const bf16x8*)(b1 + k);
        acc00 = __builtin_amdgcn_mfma_f32_16x16x32_bf16(af0, bf0, acc00, 0, 0, 0);
        acc01 = __builtin_amdgcn_mfma_f32_16x16x32_bf16(af0, bf1, acc01, 0, 0, 0);
        acc10 = __builtin_amdgcn_mfma_f32_16x16x32_bf16(af1, bf0, acc10, 0, 0, 0);
        acc11 = __builtin_amdgcn_mfma_f32_16x16x32_bf16(af1, bf1, acc11, 0, 0, 0);
    }

    // C/D layout (m89-verified): col = lane&15, row = quad*4 + reg
    #define STORE_TILE(ACC, TM, TN)                                            \
    {                                                                          \
        int col  = bn + wn + (TN) * 16 + l15;                                  \
        int rowb = bm + wm + (TM) * 16 + quad * 4;                             \
        _Pragma("unroll")                                                      \
        for (int i = 0; i < 4; ++i) {                                          \
            int r = rowb + i;                                                  \
            if (r < M) {                                                       \
                float v = (ACC)[i];                                            \
                if (outF) {                                                    \
                    v += bias[col];                                            \
                    v = v > 0.f ? v : expm1f(v);                               \
                    outF[(size_t)r * N + col] = v;                             \
                } else {                                                       \
                    outB[(size_t)r * N + col] = f2bf(v);                       \
                }                                                              \
            }                                                                  \
        }                                                                      \
    }
    STORE_TILE(acc00, 0, 0)
    STORE_TILE(acc01, 0, 1)
    STORE_TILE(acc10, 1, 0)
    STORE_TILE(acc11, 1, 1)
    #undef STORE_TILE
}

// ---------------------------------------------------------------------------
// bf16 sparse aggregation over destination-sorted CSR. One wave per node,
// lane owns 8 bf16 features (512 = 64*8). fp32 accumulate, bf16 out.
// gcn=1: out = celu(dinv^2*h[c] + sum n_g*h[src] + bias)
// gcn=0: out = sA * (sum nrm*h[src]) + sB * other[c]
// ---------------------------------------------------------------------------
__global__ __launch_bounds__(64) void k_bagg(
    const ushort_t* __restrict__ h, int hs,
    const int* __restrict__ srcs, const float* __restrict__ nrm,
    const int* __restrict__ rp, const float* __restrict__ dinv_g,
    const float* __restrict__ bias,
    const ushort_t* __restrict__ other, int os,
    ushort_t* __restrict__ out, int outs,
    float sA, float sB, int gcn)
{
    const int c = blockIdx.x;
    const int f = threadIdx.x << 3;
    float acc[8] = {0.f, 0.f, 0.f, 0.f, 0.f, 0.f, 0.f, 0.f};
    float v[8];
    if (gcn) {
        float dv = dinv_g[c];
        float d2 = dv * dv;
        uint4 u = *(const uint4*)(h + (size_t)c * hs + f);
        bf2f8(u, v);
        #pragma unroll
        for (int i = 0; i < 8; ++i) acc[i] = d2 * v[i];
    }
    const int e1 = rp[c + 1];
    for (int e = rp[c]; e < e1; ++e) {
        int s = srcs[e];
        float nv = nrm[e];
        uint4 u = *(const uint4*)(h + (size_t)s * hs + f);
        bf2f8(u, v);
        #pragma unroll
        for (int i = 0; i < 8; ++i) acc[i] = fmaf(nv, v[i], acc[i]);
    }
    float r[8];
    if (gcn) {
        #pragma unroll
        for (int i = 0; i < 8; ++i) {
            float x = acc[i] + bias[f + i];
            r[i] = x > 0.f ? x : expm1f(x);
        }
    } else {
        float o[8] = {0.f, 0.f, 0.f, 0.f, 0.f, 0.f, 0.f, 0.f};
        if (other) {
            uint4 u = *(const uint4*)(other + (size_t)c * os + f);
            bf2f8(u, o);
        }
        #pragma unroll
        for (int i = 0; i < 8; ++i) r[i] = fmaf(sA, acc[i], sB * o[i]);
    }
    *(uint4*)(out + (size_t)c * outs + f) = f2bf8v(r);
}

// ---------------------------------------------------------------------------

extern "C" void kernel_launch(void* const* d_in, const int* in_sizes, int n_in,
                              void* d_out, int out_size, void* d_ws, size_t ws_size,
                              hipStream_t stream) {
    const float* x  = (const float*)d_in[0];
    const int*   ei = (const int*)d_in[1];
    const float* ew = (const float*)d_in[2];
    const float* W1 = (const float*)d_in[3];
    const float* b1 = (const float*)d_in[4];
    const float* W2 = (const float*)d_in[5];
    const float* b2 = (const float*)d_in[6];
    const float* Wc = (const float*)d_in[7];
    const float* bc = (const float*)d_in[8];
    float* out = (float*)d_out;

    const int* row = ei;
    const int* col = ei + N_EDGES;

    char* ws = (char*)d_ws;
    size_t off = 0;
    auto alloc = [&](size_t bytes) -> void* {
        void* p = ws + off;
        off += (bytes + 255) & ~(size_t)255;
        return p;
    };
    ushort_t* xb   = (ushort_t*)alloc((size_t)N_NODES * FDIM * 2);
    ushort_t* bufA = (ushort_t*)alloc((size_t)N_NODES * FDIM * 2);   // h1 / h2
    ushort_t* bufB = (ushort_t*)alloc((size_t)N_NODES * FDIM * 2);   // h1a
    ushort_t* Tbuf = (ushort_t*)alloc((size_t)N_NODES * 3 * FDIM * 2); // [T0|T1|T2]
    ushort_t* W1t  = (ushort_t*)alloc((size_t)FDIM * FDIM * 2);
    ushort_t* W2t  = (ushort_t*)alloc((size_t)FDIM * FDIM * 2);
    ushort_t* Wct  = (ushort_t*)alloc((size_t)DOUT * 3 * FDIM * 2);
    float* deg_g  = (float*)alloc((size_t)N_NODES * 4);
    float* deg_c  = (float*)alloc((size_t)N_NODES * 4);
    float* dinv_g = (float*)alloc((size_t)N_NODES * 4);
    float* dinv_c = (float*)alloc((size_t)N_NODES * 4);
    int*   counts = (int*)alloc((size_t)N_NODES * 4);
    int*   fill   = (int*)alloc((size_t)N_NODES * 4);
    int*   rp     = (int*)alloc((size_t)(N_NODES + 1) * 4);
    int*   srcs   = (int*)alloc((size_t)N_EDGES * 4);
    float* n_g    = (float*)alloc((size_t)N_EDGES * 4);
    float* n_c    = (float*)alloc((size_t)N_EDGES * 4);

    const int TB = 256;
    dim3 nodeGrid((N_NODES + TB - 1) / TB);
    dim3 edgeGrid((N_EDGES + TB - 1) / TB);

    // ---- preprocessing ----
    hipLaunchKernelGGL(k_zero, nodeGrid, dim3(TB), 0, stream, deg_g, deg_c, counts, fill, N_NODES);
    hipLaunchKernelGGL(k_edge_deg, edgeGrid, dim3(TB), 0, stream, row, col, ew, deg_g, deg_c, counts, N_EDGES);
    hipLaunchKernelGGL(k_dinv, nodeGrid, dim3(TB), 0, stream, deg_g, deg_c, dinv_g, dinv_c, N_NODES);
    hipLaunchKernelGGL(k_scan, dim3(1), dim3(1024), 0, stream, counts, rp, N_NODES);
    hipLaunchKernelGGL(k_fill, edgeGrid, dim3(TB), 0, stream, row, col, ew, dinv_g, dinv_c,
                       rp, fill, srcs, n_g, n_c, N_EDGES);

    // ---- conversions ----
    {
        int n4 = N_NODES * FDIM / 4;
        hipLaunchKernelGGL(k_f2b, dim3((n4 + TB - 1) / TB), dim3(TB), 0, stream, x, xb, n4);
        int nw = FDIM * FDIM;
        hipLaunchKernelGGL(k_wt, dim3((nw + TB - 1) / TB), dim3(TB), 0, stream, W1, W1t, FDIM, FDIM);
        hipLaunchKernelGGL(k_wt, dim3((nw + TB - 1) / TB), dim3(TB), 0, stream, W2, W2t, FDIM, FDIM);
        int nc = 3 * FDIM * DOUT;
        hipLaunchKernelGGL(k_wc, dim3((nc + TB - 1) / TB), dim3(TB), 0, stream, Wc, Wct);
    }

    auto bgemm = [&](const ushort_t* A, const ushort_t* Bt, int M, int K, int N,
                     const float* bias, ushort_t* oB, float* oF) {
        int mb = (M + 63) >> 6, chunk = (mb + 7) >> 3, nyb = N >> 6;
        hipLaunchKernelGGL(k_bgemm, dim3(8 * chunk * nyb), dim3(256), 0, stream,
                           A, Bt, M, K, N, bias, oB, oF);
    };

    // ---- GCN layer 1 ----
    bgemm(xb, W1t, N_NODES, FDIM, FDIM, nullptr, bufA, nullptr);          // h1 = x@W1
    hipLaunchKernelGGL(k_bagg, dim3(N_NODES), dim3(64), 0, stream,
                       bufA, FDIM, srcs, n_g, rp, dinv_g, b1,
                       (const ushort_t*)nullptr, 0, bufB, FDIM, 1.f, 0.f, 1);  // h1a

    // ---- GCN layer 2 ----
    bgemm(bufB, W2t, N_NODES, FDIM, FDIM, nullptr, bufA, nullptr);        // h2 = h1a@W2
    hipLaunchKernelGGL(k_bagg, dim3(N_NODES), dim3(64), 0, stream,
                       bufA, FDIM, srcs, n_g, rp, dinv_g, b2,
                       (const ushort_t*)nullptr, 0, Tbuf, 3 * FDIM, 1.f, 0.f, 1); // T0

    // ---- Cheb: T1 = lhat(T0); T2 = 2*lhat(T1) - T0 (all in Tbuf) ----
    hipLaunchKernelGGL(k_bagg, dim3(N_NODES), dim3(64), 0, stream,
                       Tbuf, 3 * FDIM, srcs, n_c, rp, (const float*)nullptr,
                       (const float*)nullptr, (const ushort_t*)nullptr, 0,
                       Tbuf + FDIM, 3 * FDIM, 1.f, 0.f, 0);               // T1
    hipLaunchKernelGGL(k_bagg, dim3(N_NODES), dim3(64), 0, stream,
                       Tbuf + FDIM, 3 * FDIM, srcs, n_c, rp, (const float*)nullptr,
                       (const float*)nullptr, Tbuf, 3 * FDIM,
                       Tbuf + 2 * FDIM, 3 * FDIM, 2.f, -1.f, 0);          // T2

    // ---- fused Cheb GEMM: out = celu([T0|T1|T2] @ Wct^T + bc), K=1536 ----
    bgemm(Tbuf, Wct, N_NODES, 3 * FDIM, DOUT, bc, nullptr, out);
}

// Round 3
// 305.892 us; speedup vs baseline: 2.0900x; 1.3651x over previous
//
#include <hip/hip_runtime.h>
#include <math.h>

#define N_NODES 10000
#define N_EDGES 160000
#define FDIM    512
#define DOUT    256

typedef unsigned short ushort_t;
typedef unsigned int   uint_t;
typedef __attribute__((ext_vector_type(8))) short bf16x8;
typedef __attribute__((ext_vector_type(4))) float f32x4;

// ---------------------------------------------------------------------------
// helpers
// ---------------------------------------------------------------------------
__device__ inline ushort_t f2bf(float f) {
    uint_t u = __float_as_uint(f);
    u += 0x7fffu + ((u >> 16) & 1u);        // round-to-nearest-even
    return (ushort_t)(u >> 16);
}
__device__ inline void bf2f8(uint4 u, float* v) {
    v[0] = __uint_as_float(u.x << 16); v[1] = __uint_as_float(u.x & 0xffff0000u);
    v[2] = __uint_as_float(u.y << 16); v[3] = __uint_as_float(u.y & 0xffff0000u);
    v[4] = __uint_as_float(u.z << 16); v[5] = __uint_as_float(u.z & 0xffff0000u);
    v[6] = __uint_as_float(u.w << 16); v[7] = __uint_as_float(u.w & 0xffff0000u);
}
__device__ inline uint4 f2bf8v(const float* v) {
    uint4 u;
    u.x = (uint_t)f2bf(v[0]) | ((uint_t)f2bf(v[1]) << 16);
    u.y = (uint_t)f2bf(v[2]) | ((uint_t)f2bf(v[3]) << 16);
    u.z = (uint_t)f2bf(v[4]) | ((uint_t)f2bf(v[5]) << 16);
    u.w = (uint_t)f2bf(v[6]) | ((uint_t)f2bf(v[7]) << 16);
    return u;
}
// async 16B global -> LDS (wave-uniform base + lane*16)
__device__ inline void gld_lds16(const ushort_t* g, ushort_t* l) {
    __builtin_amdgcn_global_load_lds(
        (const __attribute__((address_space(1))) unsigned int*)g,
        (__attribute__((address_space(3))) unsigned int*)l,
        16, 0, 0);
}

// ---------------------------------------------------------------------------
// Preprocessing: degrees, norms, destination-sorted CSR
// ---------------------------------------------------------------------------
__global__ void k_zero(float* deg_g, float* deg_c, int* counts, int* fill, int n) {
    int i = blockIdx.x * blockDim.x + threadIdx.x;
    if (i < n) { deg_g[i] = 0.f; deg_c[i] = 0.f; counts[i] = 0; fill[i] = 0; }
}

__global__ void k_edge_deg(const int* __restrict__ row, const int* __restrict__ col,
                           const float* __restrict__ w,
                           float* deg_g, float* deg_c, int* counts, int E) {
    int e = blockIdx.x * blockDim.x + threadIdx.x;
    if (e >= E) return;
    int r = row[e], c = col[e];
    float wv = w[e];
    atomicAdd(&deg_g[c], wv);
    if (r != c) atomicAdd(&deg_c[r], wv);
    atomicAdd(&counts[c], 1);
}

__global__ void k_dinv(const float* __restrict__ deg_g, const float* __restrict__ deg_c,
                       float* dinv_g, float* dinv_c, int n) {
    int i = blockIdx.x * blockDim.x + threadIdx.x;
    if (i >= n) return;
    dinv_g[i] = rsqrtf(deg_g[i] + 1.0f);
    float d = deg_c[i];
    dinv_c[i] = d > 0.f ? rsqrtf(d) : 0.f;
}

// two-level scan: local block scans -> scan of 40 partials -> add offsets
__global__ __launch_bounds__(256) void k_scan1(const int* __restrict__ counts,
                                               int* __restrict__ rp,
                                               int* __restrict__ part, int n) {
    __shared__ int s[256];
    int tid = threadIdx.x;
    int i = blockIdx.x * 256 + tid;
    int v = (i < n) ? counts[i] : 0;
    s[tid] = v;
    __syncthreads();
    for (int o = 1; o < 256; o <<= 1) {
        int t = (tid >= o) ? s[tid - o] : 0;
        __syncthreads();
        s[tid] += t;
        __syncthreads();
    }
    if (i < n) rp[i] = s[tid] - v;          // local exclusive
    if (tid == 255) part[blockIdx.x] = s[255];
}

__global__ __launch_bounds__(64) void k_scan2(int* __restrict__ part,
                                              int* __restrict__ rp, int nb, int n) {
    int tid = threadIdx.x;
    int v = (tid < nb) ? part[tid] : 0;
    int x = v;
    for (int o = 1; o < 64; o <<= 1) {
        int y = __shfl_up(x, o, 64);
        if (tid >= o) x += y;
    }
    if (tid < nb) part[tid] = x - v;        // exclusive block offsets
    if (tid == 63) rp[n] = x;               // total
}

__global__ __launch_bounds__(256) void k_scan3(int* __restrict__ rp,
                                               const int* __restrict__ part, int n) {
    int i = blockIdx.x * 256 + threadIdx.x;
    if (i < n) rp[i] += part[blockIdx.x];
}

// edge records: (src, norm) packed 8B. n_c stored negated.
__global__ void k_fill(const int* __restrict__ row, const int* __restrict__ col,
                       const float* __restrict__ w,
                       const float* __restrict__ dinv_g, const float* __restrict__ dinv_c,
                       const int* __restrict__ rp, int* __restrict__ fill,
                       int2* __restrict__ eg, int2* __restrict__ ec, int E) {
    int e = blockIdx.x * blockDim.x + threadIdx.x;
    if (e >= E) return;
    int r = row[e], c = col[e];
    float wv = w[e];
    float ng = dinv_g[r] * wv * dinv_g[c];
    float w0 = (r == c) ? 0.f : wv;
    float nc = -(dinv_c[r] * w0 * dinv_c[c]);
    int pos = rp[c] + atomicAdd(&fill[c], 1);
    eg[pos] = make_int2(r, __float_as_int(ng));
    ec[pos] = make_int2(r, __float_as_int(nc));
}

// ---------------------------------------------------------------------------
// conversions / weight repack
// ---------------------------------------------------------------------------
__global__ void k_f2b(const float* __restrict__ src, ushort_t* __restrict__ dst, int n4) {
    int i = blockIdx.x * blockDim.x + threadIdx.x;
    if (i >= n4) return;
    float4 v = *(const float4*)(src + (size_t)i * 4);
    uint2 p;
    p.x = (uint_t)f2bf(v.x) | ((uint_t)f2bf(v.y) << 16);
    p.y = (uint_t)f2bf(v.z) | ((uint_t)f2bf(v.w) << 16);
    *(uint2*)(dst + (size_t)i * 4) = p;
}

// W[K][N] fp32 -> Wt[N][K] bf16
__global__ void k_wt(const float* __restrict__ W, ushort_t* __restrict__ Wt, int K, int N) {
    int t = blockIdx.x * blockDim.x + threadIdx.x;
    if (t >= K * N) return;
    int n = t % N, k = t / N;
    Wt[(size_t)n * K + k] = f2bf(W[(size_t)k * N + n]);
}

// Wc[3][512][256] fp32 -> Wct[256][1536] bf16: Wct[n][kk*512+d] = Wc[kk][d][n]
__global__ void k_wc(const float* __restrict__ Wc, ushort_t* __restrict__ Wct) {
    int t = blockIdx.x * blockDim.x + threadIdx.x;
    if (t >= 3 * 512 * 256) return;
    int n = t & 255, d = (t >> 8) & 511, kk = t >> 17;
    Wct[(size_t)n * 1536 + kk * 512 + d] = f2bf(Wc[((size_t)kk * 512 + d) * 256 + n]);
}

// ---------------------------------------------------------------------------
// Staged bf16 MFMA GEMM (m97 structure): 64x128 tile, BK=32, 256 thr = 4 waves
// (each 32x64 = 2x4 MFMA tiles). global_load_lds width-16 staging, single
// LDS buffer, 2 barriers/iter. A[M][lda] bf16, Bt[N][ldb] bf16 (B transposed).
// ---------------------------------------------------------------------------
#define BM 64
#define BN 128
#define BK 32

__global__ __launch_bounds__(256) void k_mgemm(
    const ushort_t* __restrict__ A, int lda,
    const ushort_t* __restrict__ Bt, int ldb,
    int M, int K, int N,
    const float* __restrict__ bias,
    ushort_t* __restrict__ outB, float* __restrict__ outF)
{
    __shared__ ushort_t As[BM * BK];   // rows of 32 bf16 (64 B), contiguous
    __shared__ ushort_t Bs[BN * BK];
    const int tid  = threadIdx.x;
    const int w    = tid >> 6;
    const int lane = tid & 63;
    const int l15  = lane & 15;
    const int quad = lane >> 4;
    const int bm = blockIdx.x * BM, bn = blockIdx.y * BN;
    const int wm = (w & 1) * 32;        // wave row offset (2 waves down)
    const int wn = (w >> 1) * 64;       // wave col offset (2 waves across)

    // staging: lane -> (row-in-16, 8-elem chunk)
    const int sr = lane >> 2;           // 0..15
    const int sc = (lane & 3) * 8;      // 0,8,16,24
    // A: wave w stages rows w*16 .. w*16+15 (1 inst)
    int arow = min(bm + w * 16 + sr, M - 1);
    const ushort_t* ag = A + (size_t)arow * lda + sc;
    ushort_t* al = As + (w * 16 + sr) * BK + sc;        // = w*1024B + lane*16B
    // B: wave w stages rows w*32 .. w*32+31 (2 insts)
    const ushort_t* bg0 = Bt + (size_t)(bn + w * 32 + sr) * ldb + sc;
    const ushort_t* bg1 = bg0 + (size_t)16 * ldb;
    ushort_t* bl0 = Bs + (w * 32 + sr) * BK + sc;
    ushort_t* bl1 = bl0 + 16 * BK;

    f32x4 acc[2][4] = {};

    for (int k0 = 0; k0 < K; k0 += BK) {
        __syncthreads();
        gld_lds16(ag + k0, al);
        gld_lds16(bg0 + k0, bl0);
        gld_lds16(bg1 + k0, bl1);
        __syncthreads();    // includes vmcnt(0) drain of global_load_lds
        bf16x8 af[2], bfr[4];
#pragma unroll
        for (int i = 0; i < 2; ++i)
            af[i] = *(const bf16x8*)(As + (wm + i * 16 + l15) * BK + quad * 8);
#pragma unroll
        for (int j = 0; j < 4; ++j)
            bfr[j] = *(const bf16x8*)(Bs + (wn + j * 16 + l15) * BK + quad * 8);
#pragma unroll
        for (int i = 0; i < 2; ++i)
#pragma unroll
            for (int j = 0; j < 4; ++j)
                acc[i][j] = __builtin_amdgcn_mfma_f32_16x16x32_bf16(af[i], bfr[j], acc[i][j], 0, 0, 0);
    }

    // epilogue — C/D layout: col = lane&15, row = quad*4 + reg (m89-verified)
#pragma unroll
    for (int i = 0; i < 2; ++i) {
        int rowb = bm + wm + i * 16 + quad * 4;
#pragma unroll
        for (int j = 0; j < 4; ++j) {
            int col = bn + wn + j * 16 + l15;
#pragma unroll
            for (int r = 0; r < 4; ++r) {
                int rr = rowb + r;
                if (rr < M) {
                    float v = acc[i][j][r];
                    if (outF) {
                        v += bias[col];
                        v = v > 0.f ? v : expm1f(v);
                        outF[(size_t)rr * N + col] = v;
                    } else {
                        outB[(size_t)rr * N + col] = f2bf(v);
                    }
                }
            }
        }
    }
}

// ---------------------------------------------------------------------------
// bf16 sparse aggregation over destination-sorted CSR. One wave per node,
// lane owns 8 bf16 features. Edge loop unrolled x4 for MLP.
// gcn=1: out = celu(dinv^2*h[c] + sum n*h[src] + bias)
// gcn=0: out = sA * (sum n*h[src]) + sB * other[c]
// ---------------------------------------------------------------------------
__global__ __launch_bounds__(64) void k_bagg(
    const ushort_t* __restrict__ h, int hs,
    const int2* __restrict__ er,
    const int* __restrict__ rp, const float* __restrict__ dinv_g,
    const float* __restrict__ bias,
    const ushort_t* __restrict__ other, int os,
    ushort_t* __restrict__ out, int outs,
    float sA, float sB, int gcn)
{
    const int c = blockIdx.x;
    const int f = threadIdx.x << 3;
    float acc[8] = {0.f, 0.f, 0.f, 0.f, 0.f, 0.f, 0.f, 0.f};
    float v0[8], v1[8], v2[8], v3[8];
    if (gcn) {
        float dv = dinv_g[c];
        float d2 = dv * dv;
        uint4 u = *(const uint4*)(h + (size_t)c * hs + f);
        bf2f8(u, v0);
#pragma unroll
        for (int i = 0; i < 8; ++i) acc[i] = d2 * v0[i];
    }
    int e = rp[c];
    const int e1 = rp[c + 1];
    for (; e + 4 <= e1; e += 4) {
        int2 p0 = er[e], p1 = er[e + 1], p2 = er[e + 2], p3 = er[e + 3];
        uint4 u0 = *(const uint4*)(h + (size_t)p0.x * hs + f);
        uint4 u1 = *(const uint4*)(h + (size_t)p1.x * hs + f);
        uint4 u2 = *(const uint4*)(h + (size_t)p2.x * hs + f);
        uint4 u3 = *(const uint4*)(h + (size_t)p3.x * hs + f);
        float n0 = __int_as_float(p0.y), n1 = __int_as_float(p1.y);
        float n2 = __int_as_float(p2.y), n3 = __int_as_float(p3.y);
        bf2f8(u0, v0); bf2f8(u1, v1); bf2f8(u2, v2); bf2f8(u3, v3);
#pragma unroll
        for (int i = 0; i < 8; ++i) {
            acc[i] = fmaf(n0, v0[i], acc[i]);
            acc[i] = fmaf(n1, v1[i], acc[i]);
            acc[i] = fmaf(n2, v2[i], acc[i]);
            acc[i] = fmaf(n3, v3[i], acc[i]);
        }
    }
    for (; e < e1; ++e) {
        int2 p = er[e];
        uint4 u = *(const uint4*)(h + (size_t)p.x * hs + f);
        float nv = __int_as_float(p.y);
        bf2f8(u, v0);
#pragma unroll
        for (int i = 0; i < 8; ++i) acc[i] = fmaf(nv, v0[i], acc[i]);
    }
    float r[8];
    if (gcn) {
#pragma unroll
        for (int i = 0; i < 8; ++i) {
            float x = acc[i] + bias[f + i];
            r[i] = x > 0.f ? x : expm1f(x);
        }
    } else {
        float o[8] = {0.f, 0.f, 0.f, 0.f, 0.f, 0.f, 0.f, 0.f};
        if (other) {
            uint4 u = *(const uint4*)(other + (size_t)c * os + f);
            bf2f8(u, o);
        }
#pragma unroll
        for (int i = 0; i < 8; ++i) r[i] = fmaf(sA, acc[i], sB * o[i]);
    }
    *(uint4*)(out + (size_t)c * outs + f) = f2bf8v(r);
}

// ---------------------------------------------------------------------------

extern "C" void kernel_launch(void* const* d_in, const int* in_sizes, int n_in,
                              void* d_out, int out_size, void* d_ws, size_t ws_size,
                              hipStream_t stream) {
    const float* x  = (const float*)d_in[0];
    const int*   ei = (const int*)d_in[1];
    const float* ew = (const float*)d_in[2];
    const float* W1 = (const float*)d_in[3];
    const float* b1 = (const float*)d_in[4];
    const float* W2 = (const float*)d_in[5];
    const float* b2 = (const float*)d_in[6];
    const float* Wc = (const float*)d_in[7];
    const float* bc = (const float*)d_in[8];
    float* out = (float*)d_out;

    const int* row = ei;
    const int* col = ei + N_EDGES;

    char* ws = (char*)d_ws;
    size_t off = 0;
    auto alloc = [&](size_t bytes) -> void* {
        void* p = ws + off;
        off += (bytes + 255) & ~(size_t)255;
        return p;
    };
    ushort_t* xb   = (ushort_t*)alloc((size_t)N_NODES * FDIM * 2);
    ushort_t* bufA = (ushort_t*)alloc((size_t)N_NODES * FDIM * 2);     // h1 / h2
    ushort_t* bufB = (ushort_t*)alloc((size_t)N_NODES * FDIM * 2);     // h1a
    ushort_t* Tbuf = (ushort_t*)alloc((size_t)N_NODES * 3 * FDIM * 2); // [T0|T1|T2]
    ushort_t* W1t  = (ushort_t*)alloc((size_t)FDIM * FDIM * 2);
    ushort_t* W2t  = (ushort_t*)alloc((size_t)FDIM * FDIM * 2);
    ushort_t* Wct  = (ushort_t*)alloc((size_t)DOUT * 3 * FDIM * 2);
    float* deg_g  = (float*)alloc((size_t)N_NODES * 4);
    float* deg_c  = (float*)alloc((size_t)N_NODES * 4);
    float* dinv_g = (float*)alloc((size_t)N_NODES * 4);
    float* dinv_c = (float*)alloc((size_t)N_NODES * 4);
    int*   counts = (int*)alloc((size_t)N_NODES * 4);
    int*   fill   = (int*)alloc((size_t)N_NODES * 4);
    int*   rp     = (int*)alloc((size_t)(N_NODES + 1) * 4);
    int*   part   = (int*)alloc(64 * 4);
    int2*  eg     = (int2*)alloc((size_t)N_EDGES * 8);
    int2*  ec     = (int2*)alloc((size_t)N_EDGES * 8);

    const int TB = 256;
    dim3 nodeGrid((N_NODES + TB - 1) / TB);
    dim3 edgeGrid((N_EDGES + TB - 1) / TB);
    int nScanB = (N_NODES + 255) / 256;

    // ---- preprocessing ----
    hipLaunchKernelGGL(k_zero, nodeGrid, dim3(TB), 0, stream, deg_g, deg_c, counts, fill, N_NODES);
    hipLaunchKernelGGL(k_edge_deg, edgeGrid, dim3(TB), 0, stream, row, col, ew, deg_g, deg_c, counts, N_EDGES);
    hipLaunchKernelGGL(k_dinv, nodeGrid, dim3(TB), 0, stream, deg_g, deg_c, dinv_g, dinv_c, N_NODES);
    hipLaunchKernelGGL(k_scan1, dim3(nScanB), dim3(256), 0, stream, counts, rp, part, N_NODES);
    hipLaunchKernelGGL(k_scan2, dim3(1), dim3(64), 0, stream, part, rp, nScanB, N_NODES);
    hipLaunchKernelGGL(k_scan3, dim3(nScanB), dim3(256), 0, stream, rp, part, N_NODES);
    hipLaunchKernelGGL(k_fill, edgeGrid, dim3(TB), 0, stream, row, col, ew, dinv_g, dinv_c,
                       rp, fill, eg, ec, N_EDGES);

    // ---- conversions ----
    {
        int n4 = N_NODES * FDIM / 4;
        hipLaunchKernelGGL(k_f2b, dim3((n4 + TB - 1) / TB), dim3(TB), 0, stream, x, xb, n4);
        int nw = FDIM * FDIM;
        hipLaunchKernelGGL(k_wt, dim3((nw + TB - 1) / TB), dim3(TB), 0, stream, W1, W1t, FDIM, FDIM);
        hipLaunchKernelGGL(k_wt, dim3((nw + TB - 1) / TB), dim3(TB), 0, stream, W2, W2t, FDIM, FDIM);
        int nc = 3 * FDIM * DOUT;
        hipLaunchKernelGGL(k_wc, dim3((nc + TB - 1) / TB), dim3(TB), 0, stream, Wc, Wct);
    }

    auto mgemm = [&](const ushort_t* A, int lda, const ushort_t* Bt, int ldb,
                     int M, int K, int N, const float* bias, ushort_t* oB, float* oF) {
        dim3 g((M + BM - 1) / BM, N / BN);
        hipLaunchKernelGGL(k_mgemm, g, dim3(256), 0, stream, A, lda, Bt, ldb, M, K, N, bias, oB, oF);
    };

    // ---- GCN layer 1 ----
    mgemm(xb, FDIM, W1t, FDIM, N_NODES, FDIM, FDIM, nullptr, bufA, nullptr);     // h1
    hipLaunchKernelGGL(k_bagg, dim3(N_NODES), dim3(64), 0, stream,
                       bufA, FDIM, eg, rp, dinv_g, b1,
                       (const ushort_t*)nullptr, 0, bufB, FDIM, 1.f, 0.f, 1);    // h1a

    // ---- GCN layer 2 ----
    mgemm(bufB, FDIM, W2t, FDIM, N_NODES, FDIM, FDIM, nullptr, bufA, nullptr);   // h2
    hipLaunchKernelGGL(k_bagg, dim3(N_NODES), dim3(64), 0, stream,
                       bufA, FDIM, eg, rp, dinv_g, b2,
                       (const ushort_t*)nullptr, 0, Tbuf, 3 * FDIM, 1.f, 0.f, 1); // T0

    // ---- Cheb recurrences ----
    hipLaunchKernelGGL(k_bagg, dim3(N_NODES), dim3(64), 0, stream,
                       Tbuf, 3 * FDIM, ec, rp, (const float*)nullptr,
                       (const float*)nullptr, (const ushort_t*)nullptr, 0,
                       Tbuf + FDIM, 3 * FDIM, 1.f, 0.f, 0);                      // T1
    hipLaunchKernelGGL(k_bagg, dim3(N_NODES), dim3(64), 0, stream,
                       Tbuf + FDIM, 3 * FDIM, ec, rp, (const float*)nullptr,
                       (const float*)nullptr, Tbuf, 3 * FDIM,
                       Tbuf + 2 * FDIM, 3 * FDIM, 2.f, -1.f, 0);                 // T2

    // ---- fused Cheb GEMM: out = celu([T0|T1|T2] @ Wct^T + bc), K=1536 ----
    mgemm(Tbuf, 3 * FDIM, Wct, 3 * FDIM, N_NODES, 3 * FDIM, DOUT, bc, nullptr, out);
}